// Round 5
// baseline (744.901 us; speedup 1.0000x reference)
//
#include <hip/hip_runtime.h>
#include <hip/hip_fp16.h>

constexpr int D_IN = 256, D_HID = 512, D_OUT = 48;
constexpr int HPAD = 64;   // padded feature stride (f16) -> 128 B rows for prop
constexpr int K_STEPS = 10;

typedef __attribute__((ext_vector_type(8))) __bf16 bf16x8;
typedef __attribute__((ext_vector_type(4))) float f32x4;

__device__ __forceinline__ unsigned short f2bf(float f) {
  unsigned u = __builtin_bit_cast(unsigned, f);
  u += 0x7fffu + ((u >> 16) & 1u);   // round-to-nearest-even
  return (unsigned short)(u >> 16);
}

// async global->LDS, 16 B per lane. lds dest must be wave-uniform base; HW adds lane*16.
__device__ __forceinline__ void gl2lds16(const unsigned short* g, unsigned short* l) {
  __builtin_amdgcn_global_load_lds(
      (const __attribute__((address_space(1))) unsigned int*)g,
      (__attribute__((address_space(3))) unsigned int*)l, 16, 0, 0);
}

// ---------------- graph build ----------------

__global__ void zero1_kernel(int* __restrict__ a, int N) {
  int i = blockIdx.x * 256 + threadIdx.x;
  if (i < N) a[i] = 0;
}

// count + rank in one pass: rank[e] = arrival order of edge e at its dst.
__global__ __launch_bounds__(256) void count_kernel(const int* __restrict__ dst,
                                                    int* __restrict__ cnt,
                                                    int* __restrict__ rank, int E) {
  int e = blockIdx.x * 256 + threadIdx.x;
  if (e >= E) return;
  int d = __builtin_nontemporal_load(dst + e);
  int r = atomicAdd(&cnt[d], 1);
  __builtin_nontemporal_store(r, rank + e);
}

__global__ void dinv_kernel(const int* __restrict__ cnt, float* __restrict__ dinv, int N) {
  int n = blockIdx.x * 256 + threadIdx.x;
  if (n < N) dinv[n] = rsqrtf((float)(cnt[n] + 1));  // +1 = self-loop
}

// exclusive scan of PADDED cnt -> row_ptr. padded = (cnt+8)&~7:
// always >= cnt+1 (room for the folded self-loop slot), multiple of 8.
__global__ void scan1_kernel(const int* __restrict__ cnt, int* __restrict__ row_ptr,
                             int* __restrict__ bsum, int N) {
  __shared__ int sd[256];
  int tid = threadIdx.x, b = blockIdx.x;
  int i0 = b * 1024 + tid * 4;
  int v[4];
#pragma unroll
  for (int m = 0; m < 4; ++m) v[m] = (i0 + m < N) ? ((cnt[i0 + m] + 8) & ~7) : 0;
  int s = v[0] + v[1] + v[2] + v[3];
  sd[tid] = s;
  __syncthreads();
  for (int off = 1; off < 256; off <<= 1) {
    int t = (tid >= off) ? sd[tid - off] : 0;
    __syncthreads();
    sd[tid] += t;
    __syncthreads();
  }
  int run = sd[tid] - s;
#pragma unroll
  for (int m = 0; m < 4; ++m) {
    if (i0 + m < N) row_ptr[i0 + m] = run;
    run += v[m];
  }
  if (tid == 255) bsum[b] = sd[255];
}

__global__ void scan2_kernel(const int* __restrict__ bsum, int* __restrict__ bofs,
                             int* __restrict__ row_ptr, int NB, int N) {
  __shared__ int sd[128];
  int tid = threadIdx.x;
  int v = (tid < NB) ? bsum[tid] : 0;
  sd[tid] = v;
  __syncthreads();
  for (int off = 1; off < 128; off <<= 1) {
    int t = (tid >= off) ? sd[tid - off] : 0;
    __syncthreads();
    sd[tid] += t;
    __syncthreads();
  }
  if (tid < NB) bofs[tid] = sd[tid] - v;
  if (tid == 127) row_ptr[N] = sd[127];
}

__global__ void scan3_kernel(int* __restrict__ row_ptr, const int* __restrict__ bofs, int N) {
  int b = blockIdx.x;
  if (b == 0) return;
  int add = bofs[b];
  int i0 = b * 1024 + threadIdx.x * 4;
#pragma unroll
  for (int m = 0; m < 4; ++m)
    if (i0 + m < N) row_ptr[i0 + m] += add;
}

// edges[p] = src index (4 B). No atomic (rank precomputed), no dinv read.
__global__ __launch_bounds__(256) void fill_kernel(
    const int* __restrict__ src, const int* __restrict__ dst,
    const int* __restrict__ row_ptr, const int* __restrict__ rank,
    int* __restrict__ edges, int E) {
  int e = blockIdx.x * 256 + threadIdx.x;
  if (e >= E) return;
  int d = __builtin_nontemporal_load(dst + e);
  int s = __builtin_nontemporal_load(src + e);
  int r = __builtin_nontemporal_load(rank + e);
  edges[row_ptr[d] + r] = s;
}

// slot cnt = the node itself (self-loop); remaining pads = dummy node N (zero row)
__global__ void pad_kernel(const int* __restrict__ cnt, const int* __restrict__ row_ptr,
                           int* __restrict__ edges, int N) {
  int n = blockIdx.x * 256 + threadIdx.x;
  if (n >= N) return;
  int a = row_ptr[n] + cnt[n];
  int b = row_ptr[n + 1];
  edges[a] = n;
  for (int p = a + 1; p < b; ++p) edges[p] = N;
}

// zero the dummy row N of both q buffers
__global__ void zrow_kernel(__half* __restrict__ a, __half* __restrict__ b, int N) {
  int t = threadIdx.x;  // 64 threads
  a[(size_t)N * HPAD + t] = __float2half(0.f);
  b[(size_t)N * HPAD + t] = __float2half(0.f);
}

// ---------------- weight convert: fragment-major layouts ----------------

__global__ void convert_w1(const float* __restrict__ W1, unsigned short* __restrict__ W1F) {
  int i = blockIdx.x * 256 + threadIdx.x;
  if (i >= D_HID * D_IN) return;
  int c = i >> 8, k = i & 255;
  int ct = c >> 6, tn = (c >> 4) & 3, l15 = c & 15;
  int kb = k >> 5, q = (k >> 3) & 3, j = k & 7;
  int lane = (q << 4) | l15;
  int dst = (((ct * 4 + tn) * 8 + kb) << 9) + lane * 8 + j;
  W1F[dst] = f2bf(W1[k * D_HID + c]);
}

__global__ void convert_w2(const float* __restrict__ W2, unsigned short* __restrict__ W2F) {
  int i = blockIdx.x * 256 + threadIdx.x;
  if (i >= D_OUT * D_HID) return;
  int n = i >> 9, k = i & 511;
  int ct = k >> 6, kk = (k >> 5) & 1, q = (k >> 3) & 3, j = k & 7;
  int tn = n >> 4, l15 = n & 15;
  int lane = (q << 4) | l15;
  int dst = (((ct * 2 + kk) * 3 + tn) << 9) + lane * 8 + j;
  W2F[dst] = f2bf(W2[k * D_OUT + n]);
}

// ---------------- fused MLP encoder: 8 waves/block, deep x-load pipeline ----------------
// (R3 version, measured 94 us.) Emits h2 = h AND q0 = dinv*h.

__global__ __launch_bounds__(512, 4) void encoder_kernel(
    const float* __restrict__ x, const float* __restrict__ b1,
    const float* __restrict__ b2, const float* __restrict__ dinvp,
    const unsigned short* __restrict__ W1F,   // 512x256 fragment-major
    const unsigned short* __restrict__ W2F,   // 48x512 fragment-major
    __half* __restrict__ h2, __half* __restrict__ qb, int N) {
  __shared__ unsigned short sW1[16384];        // 32 KB: current ct chunk
  __shared__ unsigned short sHid[8][16][72];   // [wave][row][col] 18.4 KB
  __shared__ float sB1[512];
  __shared__ float sB2[64];

  int tid = threadIdx.x;
  int w = tid >> 6, lane = tid & 63;
  int q = lane >> 4, l15 = lane & 15;
  int row0 = blockIdx.x * 128 + w * 16;

  // issue ct=0 staging first: hides under the x-load phase
  {
    const unsigned short* gsrc = W1F + (w << 9) + lane * 8;
    unsigned short* ldst = &sW1[w << 9];
#pragma unroll
    for (int i = 0; i < 4; ++i)
      gl2lds16(gsrc + (i << 12), ldst + (i << 12));
  }
  sB1[tid] = b1[tid];
  if (tid < 48) sB2[tid] = b2[tid];

  // x ingest: 16 independent float4 loads issued before any conversion
  int grow = row0 + l15;
  bool rok = grow < N;
  const float* xr = x + (size_t)grow * D_IN;
  float4 xv[16];
#pragma unroll
  for (int jb = 0; jb < 8; ++jb) {
    xv[2 * jb]     = rok ? *(const float4*)(xr + jb * 32 + q * 8)
                         : make_float4(0.f, 0.f, 0.f, 0.f);
    xv[2 * jb + 1] = rok ? *(const float4*)(xr + jb * 32 + q * 8 + 4)
                         : make_float4(0.f, 0.f, 0.f, 0.f);
  }
  uint4 axu[8];
#pragma unroll
  for (int jb = 0; jb < 8; ++jb) {
    union { uint4 u; unsigned short s[8]; } uu;
    float4 v0 = xv[2 * jb], v1 = xv[2 * jb + 1];
    uu.s[0] = f2bf(v0.x); uu.s[1] = f2bf(v0.y); uu.s[2] = f2bf(v0.z); uu.s[3] = f2bf(v0.w);
    uu.s[4] = f2bf(v1.x); uu.s[5] = f2bf(v1.y); uu.s[6] = f2bf(v1.z); uu.s[7] = f2bf(v1.w);
    axu[jb] = uu.u;
  }

  f32x4 hacc[3];
#pragma unroll
  for (int t = 0; t < 3; ++t)
#pragma unroll
    for (int r = 0; r < 4; ++r) hacc[t][r] = 0.f;

  __syncthreads();   // ct=0 staged (vmcnt drained) + biases visible

  for (int ct = 0; ct < 8; ++ct) {
    int c0 = ct * 64;
    f32x4 acc[4];
#pragma unroll
    for (int t = 0; t < 4; ++t)
#pragma unroll
      for (int r = 0; r < 4; ++r) acc[t][r] = 0.f;

    const unsigned short* sb = &sW1[lane * 8];
#pragma unroll
    for (int kb = 0; kb < 8; ++kb) {
      bf16x8 a = __builtin_bit_cast(bf16x8, axu[kb]);
      bf16x8 bq0 = *(const bf16x8*)(sb + (kb << 9));
      bf16x8 bq1 = *(const bf16x8*)(sb + (kb << 9) + 4096);
      bf16x8 bq2 = *(const bf16x8*)(sb + (kb << 9) + 8192);
      bf16x8 bq3 = *(const bf16x8*)(sb + (kb << 9) + 12288);
      acc[0] = __builtin_amdgcn_mfma_f32_16x16x32_bf16(a, bq0, acc[0], 0, 0, 0);
      acc[1] = __builtin_amdgcn_mfma_f32_16x16x32_bf16(a, bq1, acc[1], 0, 0, 0);
      acc[2] = __builtin_amdgcn_mfma_f32_16x16x32_bf16(a, bq2, acc[2], 0, 0, 0);
      acc[3] = __builtin_amdgcn_mfma_f32_16x16x32_bf16(a, bq3, acc[3], 0, 0, 0);
    }
    // relu(acc + b1) -> wave-private sHid (C-layout: col=l15, row=q*4+rg)
#pragma unroll
    for (int tn = 0; tn < 4; ++tn) {
      int c = tn * 16 + l15;
      float bias = sB1[c0 + c];
#pragma unroll
      for (int rg = 0; rg < 4; ++rg) {
        float v = acc[tn][rg] + bias;
        v = v > 0.f ? v : 0.f;
        sHid[w][q * 4 + rg][c] = f2bf(v);
      }
    }
    // GEMM2 on this 64-col hid chunk (A from LDS, B direct from W2F)
#pragma unroll
    for (int kk = 0; kk < 2; ++kk) {
      bf16x8 a0 = *(const bf16x8*)&sHid[w][l15][kk * 32 + q * 8];
      const unsigned short* w2b = W2F + (((ct * 2 + kk) * 3) << 9) + lane * 8;
#pragma unroll
      for (int tn = 0; tn < 3; ++tn) {
        bf16x8 b = *(const bf16x8*)(w2b + (tn << 9));
        hacc[tn] = __builtin_amdgcn_mfma_f32_16x16x32_bf16(a0, b, hacc[tn], 0, 0, 0);
      }
    }
    // stage next ct chunk
    __syncthreads();   // all waves done reading sW1
    if (ct < 7) {
      const unsigned short* gsrc = W1F + ((size_t)(ct + 1) << 14) + (w << 9) + lane * 8;
      unsigned short* ldst = &sW1[w << 9];
#pragma unroll
      for (int i = 0; i < 4; ++i)
        gl2lds16(gsrc + (i << 12), ldst + (i << 12));
      __syncthreads();   // staged data visible
    }
  }
  // epilogue: h2 = f16(h), qb = f16(dinv*h); pad cols 48..63 zeroed in both
  float dv[4];
#pragma unroll
  for (int rg = 0; rg < 4; ++rg) {
    int gr = row0 + q * 4 + rg;
    dv[rg] = (gr < N) ? dinvp[gr] : 0.f;
  }
#pragma unroll
  for (int tn = 0; tn < 3; ++tn) {
    int c = tn * 16 + l15;
    float bias = sB2[c];
#pragma unroll
    for (int rg = 0; rg < 4; ++rg) {
      int gr = row0 + q * 4 + rg;
      if (gr < N) {
        float val = hacc[tn][rg] + bias;
        h2[(size_t)gr * HPAD + c] = __float2half(val);
        qb[(size_t)gr * HPAD + c] = __float2half(dv[rg] * val);
      }
    }
  }
#pragma unroll
  for (int rg = 0; rg < 4; ++rg) {
    int gr = row0 + q * 4 + rg;
    if (gr < N) {
      h2[(size_t)gr * HPAD + 48 + l15] = __float2half(0.f);
      qb[(size_t)gr * HPAD + 48 + l15] = __float2half(0.f);
    }
  }
}

// ---------------- APPNP propagation in q-space: 1 node/wave, 8 slots x 8 lanes ----
// Degree padded to mult-8: every slot in [p0,p1) is valid (real edge, self, or
// dummy row N = hot zero line) -> NO bound checks or weight selects in the
// inner loop. 2-deep row pipeline + 4-deep edge-index pipeline, register-
// rotated (static indices). out = 0.9*di*sum(q) + 0.1*h; nxt stores di*out.

__global__ __launch_bounds__(256) void prop_kernel(
    const __half* __restrict__ cur, const __half* __restrict__ h2,
    const float* __restrict__ dinv, const int* __restrict__ row_ptr,
    const int* __restrict__ edges, __half* __restrict__ nxt,
    float* __restrict__ outf, int N, int last) {
  int wid = (blockIdx.x * 256 + threadIdx.x) >> 6;   // 1 node per wave
  int lane = threadIdx.x & 63;
  int slot = lane >> 3;       // 0..7
  int s = lane & 7;           // 16-B feature segment
  int node = wid;
  if (node >= N) return;      // wave-uniform
  int2 pp = *(const int2*)(row_ptr + node);
  int p = pp.x + slot;
  int nb = (pp.y - pp.x) >> 3;   // >= 1 always

  float acc[8];
#pragma unroll
  for (int i = 0; i < 8; ++i) acc[i] = 0.f;

  union F4 { float4 f; __half2 h[4]; };
  // edge-index pipeline (4 deep) + row pipeline (2 deep)
  int e1 = (1 < nb) ? edges[p + 8]  : N;
  int e2 = (2 < nb) ? edges[p + 16] : N;
  int e3 = (3 < nb) ? edges[p + 24] : N;
  int e0 = edges[p];
  F4 ucur;
  ucur.f = *(const float4*)(cur + ((size_t)e0 << 6) + s * 8);

  for (int g = 0; g < nb; ++g) {
    int en = (g + 4 < nb) ? edges[p + ((g + 4) << 3)] : N;
    F4 unx;
    if (g + 1 < nb)
      unx.f = *(const float4*)(cur + ((size_t)e1 << 6) + s * 8);
    else
      unx.f = make_float4(0.f, 0.f, 0.f, 0.f);
#pragma unroll
    for (int i = 0; i < 4; ++i) {
      float2 f = __half22float2(ucur.h[i]);
      acc[2 * i]     += f.x;
      acc[2 * i + 1] += f.y;
    }
    ucur = unx;
    e1 = e2; e2 = e3; e3 = en;
  }

  // fold 8 slots (lane bits 3,4 via swizzle; bit 5 via shfl_xor)
#pragma unroll
  for (int i = 0; i < 8; ++i) {
    acc[i] += __int_as_float(__builtin_amdgcn_ds_swizzle(__float_as_int(acc[i]), 0x201F)); // ^8
    acc[i] += __int_as_float(__builtin_amdgcn_ds_swizzle(__float_as_int(acc[i]), 0x401F)); // ^16
    acc[i] += __shfl_xor(acc[i], 32);                                                      // ^32
  }
  if ((lane & 56) != 0) return;   // lanes 0..7 write the row
  float di = dinv[node];
  size_t base = ((size_t)node << 6) + s * 8;
  union { float4 f; __half2 h[4]; } uh;
  uh.f = *(const float4*)(h2 + base);
  float outv[8];
#pragma unroll
  for (int i = 0; i < 4; ++i) {
    float2 hf = __half22float2(uh.h[i]);
    outv[2 * i]     = 0.9f * di * acc[2 * i]     + 0.1f * hf.x;
    outv[2 * i + 1] = 0.9f * di * acc[2 * i + 1] + 0.1f * hf.y;
  }
  if (last) {
    if (s < 6) {  // only the 48 real features
      float* op = outf + (size_t)node * D_OUT + s * 8;
      *(float4*)op       = make_float4(outv[0], outv[1], outv[2], outv[3]);
      *(float4*)(op + 4) = make_float4(outv[4], outv[5], outv[6], outv[7]);
    }
  } else {
    union { uint4 u4; __half2 h[4]; } o;
#pragma unroll
    for (int i = 0; i < 4; ++i)
      o.h[i] = __floats2half2_rn(di * outv[2 * i], di * outv[2 * i + 1]);
    *(uint4*)(nxt + base) = o.u4;
  }
}

// ---------------- launch ----------------

extern "C" void kernel_launch(void* const* d_in, const int* in_sizes, int n_in,
                              void* d_out, int out_size, void* d_ws, size_t ws_size,
                              hipStream_t stream) {
  (void)n_in; (void)out_size; (void)ws_size;
  const float* x  = (const float*)d_in[0];
  const int*   ei = (const int*)d_in[1];
  const float* W1 = (const float*)d_in[2];
  const float* b1 = (const float*)d_in[3];
  const float* W2 = (const float*)d_in[4];
  const float* b2 = (const float*)d_in[5];
  const int N = in_sizes[0] / D_IN;
  const int E = in_sizes[1] / 2;
  const int* e_src = ei;
  const int* e_dst = ei + E;

  char* ws = (char*)d_ws;
  size_t off = 0;
  auto take = [&](size_t bytes) -> char* {
    char* p = ws + off;
    off += (bytes + 511) & ~(size_t)511;
    return p;
  };
  int* cnt      = (int*)take((size_t)N * 4);
  float* dinv   = (float*)take((size_t)N * 4);
  int* row_ptr  = (int*)take((size_t)(N + 1) * 4);
  int* bsum     = (int*)take(1024);
  int* bofs     = (int*)take(1024);
  int* rank     = (int*)take((size_t)E * 4);
  int* edges    = (int*)take(((size_t)E + 8 * (size_t)N + 2048) * 4);  // padded CSR (4-B recs)
  unsigned short* W1F = (unsigned short*)take((size_t)D_IN * D_HID * 2);
  unsigned short* W2F = (unsigned short*)take((size_t)D_HID * D_OUT * 2);
  __half* h2    = (__half*)take((size_t)N * HPAD * 2);
  __half* bufA  = (__half*)take((size_t)(N + 1) * HPAD * 2);
  __half* bufB  = (__half*)d_out;   // 19.2 MB f32 out region holds (N+1)*128B f16 buf;
                                    // it10 reads bufA and writes f32 here -> no alias
  float* outp   = (float*)d_out;

  int nb256 = (N + 255) / 256;
  int eb256 = (E + 255) / 256;
  int NB    = (N + 1023) / 1024;   // 98 <= 128 ok

  // graph build (padded CSR, q-space: 4-B edge records, self-loop folded in)
  zero1_kernel<<<nb256, 256, 0, stream>>>(cnt, N);
  count_kernel<<<eb256, 256, 0, stream>>>(e_dst, cnt, rank, E);
  dinv_kernel<<<nb256, 256, 0, stream>>>(cnt, dinv, N);
  scan1_kernel<<<NB, 256, 0, stream>>>(cnt, row_ptr, bsum, N);
  scan2_kernel<<<1, 128, 0, stream>>>(bsum, bofs, row_ptr, NB, N);
  scan3_kernel<<<NB, 256, 0, stream>>>(row_ptr, bofs, N);
  fill_kernel<<<eb256, 256, 0, stream>>>(e_src, e_dst, row_ptr, rank, edges, E);
  pad_kernel<<<nb256, 256, 0, stream>>>(cnt, row_ptr, edges, N);
  zrow_kernel<<<1, 64, 0, stream>>>(bufA, bufB, N);

  // weight permute + encoder (emits h2 and q0 into bufB)
  convert_w1<<<(D_IN * D_HID + 255) / 256, 256, 0, stream>>>(W1, W1F);
  convert_w2<<<(D_HID * D_OUT + 255) / 256, 256, 0, stream>>>(W2, W2F);
  encoder_kernel<<<(N + 127) / 128, 512, 0, stream>>>(x, b1, b2, dinv, W1F, W2F,
                                                      h2, bufB, N);

  // APPNP: 10 iters in q-space; q0(bufB) -> A -> B -> ... ; last writes f32 d_out
  int pblocks = (N + 3) / 4;   // 1 node/wave, 4 waves/block
  const __half* src = bufB;
  __half* dst = bufA;
  for (int it = 1; it <= K_STEPS; ++it) {
    int last = (it == K_STEPS);
    prop_kernel<<<pblocks, 256, 0, stream>>>(src, h2, dinv, row_ptr, edges,
                                             dst, outp, N, last);
    src = dst;
    dst = (dst == bufA) ? bufB : bufA;
  }
}

// Round 6
// 651.104 us; speedup vs baseline: 1.1441x; 1.1441x over previous
//
#include <hip/hip_runtime.h>
#include <hip/hip_fp16.h>

constexpr int D_IN = 256, D_HID = 512, D_OUT = 48;
constexpr int HPAD = 64;   // padded feature stride (f16) -> 128 B rows for prop
constexpr int K_STEPS = 10;

typedef __attribute__((ext_vector_type(8))) __bf16 bf16x8;
typedef __attribute__((ext_vector_type(4))) float f32x4;

__device__ __forceinline__ unsigned short f2bf(float f) {
  unsigned u = __builtin_bit_cast(unsigned, f);
  u += 0x7fffu + ((u >> 16) & 1u);   // round-to-nearest-even
  return (unsigned short)(u >> 16);
}

// async global->LDS, 16 B per lane. lds dest must be wave-uniform base; HW adds lane*16.
__device__ __forceinline__ void gl2lds16(const unsigned short* g, unsigned short* l) {
  __builtin_amdgcn_global_load_lds(
      (const __attribute__((address_space(1))) unsigned int*)g,
      (__attribute__((address_space(3))) unsigned int*)l, 16, 0, 0);
}

// ---------------- graph build ----------------

__global__ void zero1_kernel(int* __restrict__ a, int N) {
  int i = blockIdx.x * 256 + threadIdx.x;
  if (i < N) a[i] = 0;
}

// count + rank in one pass: rank[e] = arrival order of edge e at its dst.
__global__ __launch_bounds__(256) void count_kernel(const int* __restrict__ dst,
                                                    int* __restrict__ cnt,
                                                    int* __restrict__ rank, int E) {
  int e = blockIdx.x * 256 + threadIdx.x;
  if (e >= E) return;
  int d = __builtin_nontemporal_load(dst + e);
  int r = atomicAdd(&cnt[d], 1);
  __builtin_nontemporal_store(r, rank + e);
}

__global__ void dinv_kernel(const int* __restrict__ cnt, float* __restrict__ dinv, int N) {
  int n = blockIdx.x * 256 + threadIdx.x;
  if (n < N) dinv[n] = rsqrtf((float)(cnt[n] + 1));  // +1 = self-loop
}

// exclusive scan of PADDED cnt -> row_ptr. padded = ((cnt+1)+3)&~3:
// always >= cnt+1 (room for the folded self-loop slot), multiple of 4.
__global__ void scan1_kernel(const int* __restrict__ cnt, int* __restrict__ row_ptr,
                             int* __restrict__ bsum, int N) {
  __shared__ int sd[256];
  int tid = threadIdx.x, b = blockIdx.x;
  int i0 = b * 1024 + tid * 4;
  int v[4];
#pragma unroll
  for (int m = 0; m < 4; ++m) v[m] = (i0 + m < N) ? ((cnt[i0 + m] + 4) & ~3) : 0;
  int s = v[0] + v[1] + v[2] + v[3];
  sd[tid] = s;
  __syncthreads();
  for (int off = 1; off < 256; off <<= 1) {
    int t = (tid >= off) ? sd[tid - off] : 0;
    __syncthreads();
    sd[tid] += t;
    __syncthreads();
  }
  int run = sd[tid] - s;
#pragma unroll
  for (int m = 0; m < 4; ++m) {
    if (i0 + m < N) row_ptr[i0 + m] = run;
    run += v[m];
  }
  if (tid == 255) bsum[b] = sd[255];
}

__global__ void scan2_kernel(const int* __restrict__ bsum, int* __restrict__ bofs,
                             int* __restrict__ row_ptr, int NB, int N) {
  __shared__ int sd[128];
  int tid = threadIdx.x;
  int v = (tid < NB) ? bsum[tid] : 0;
  sd[tid] = v;
  __syncthreads();
  for (int off = 1; off < 128; off <<= 1) {
    int t = (tid >= off) ? sd[tid - off] : 0;
    __syncthreads();
    sd[tid] += t;
    __syncthreads();
  }
  if (tid < NB) bofs[tid] = sd[tid] - v;
  if (tid == 127) row_ptr[N] = sd[127];
}

__global__ void scan3_kernel(int* __restrict__ row_ptr, const int* __restrict__ bofs, int N) {
  int b = blockIdx.x;
  if (b == 0) return;
  int add = bofs[b];
  int i0 = b * 1024 + threadIdx.x * 4;
#pragma unroll
  for (int m = 0; m < 4; ++m)
    if (i0 + m < N) row_ptr[i0 + m] += add;
}

// edges[p] = src index (4 B). No atomic (rank precomputed), no dinv read.
__global__ __launch_bounds__(256) void fill_kernel(
    const int* __restrict__ src, const int* __restrict__ dst,
    const int* __restrict__ row_ptr, const int* __restrict__ rank,
    int* __restrict__ edges, int E) {
  int e = blockIdx.x * 256 + threadIdx.x;
  if (e >= E) return;
  int d = __builtin_nontemporal_load(dst + e);
  int s = __builtin_nontemporal_load(src + e);
  int r = __builtin_nontemporal_load(rank + e);
  edges[row_ptr[d] + r] = s;
}

// slot cnt = the node itself (self-loop); remaining pads = dummy node N (zero row)
__global__ void pad_kernel(const int* __restrict__ cnt, const int* __restrict__ row_ptr,
                           int* __restrict__ edges, int N) {
  int n = blockIdx.x * 256 + threadIdx.x;
  if (n >= N) return;
  int a = row_ptr[n] + cnt[n];
  int b = row_ptr[n + 1];
  edges[a] = n;
  for (int p = a + 1; p < b; ++p) edges[p] = N;
}

// zero the dummy row N of both q buffers
__global__ void zrow_kernel(__half* __restrict__ a, __half* __restrict__ b, int N) {
  int t = threadIdx.x;  // 64 threads
  a[(size_t)N * HPAD + t] = __float2half(0.f);
  b[(size_t)N * HPAD + t] = __float2half(0.f);
}

// ---------------- weight convert: fragment-major layouts ----------------

__global__ void convert_w1(const float* __restrict__ W1, unsigned short* __restrict__ W1F) {
  int i = blockIdx.x * 256 + threadIdx.x;
  if (i >= D_HID * D_IN) return;
  int c = i >> 8, k = i & 255;
  int ct = c >> 6, tn = (c >> 4) & 3, l15 = c & 15;
  int kb = k >> 5, q = (k >> 3) & 3, j = k & 7;
  int lane = (q << 4) | l15;
  int dst = (((ct * 4 + tn) * 8 + kb) << 9) + lane * 8 + j;
  W1F[dst] = f2bf(W1[k * D_HID + c]);
}

__global__ void convert_w2(const float* __restrict__ W2, unsigned short* __restrict__ W2F) {
  int i = blockIdx.x * 256 + threadIdx.x;
  if (i >= D_OUT * D_HID) return;
  int n = i >> 9, k = i & 511;
  int ct = k >> 6, kk = (k >> 5) & 1, q = (k >> 3) & 3, j = k & 7;
  int tn = n >> 4, l15 = n & 15;
  int lane = (q << 4) | l15;
  int dst = (((ct * 2 + kk) * 3 + tn) << 9) + lane * 8 + j;
  W2F[dst] = f2bf(W2[k * D_OUT + n]);
}

// ---------------- fused MLP encoder: 8 waves/block, deep x-load pipeline ----------------
// __launch_bounds__(512, 2): lift the VGPR cap to ~256 so the 16 x-loads stay
// resident and in flight (at (512,4) the compiler clamped to 64 VGPR and
// serialized them -> latency-bound at 87 us). 1 block/CU, ILP over TLP.
// Emits h2 = h AND q0 = dinv*h.

__global__ __launch_bounds__(512, 2) void encoder_kernel(
    const float* __restrict__ x, const float* __restrict__ b1,
    const float* __restrict__ b2, const float* __restrict__ dinvp,
    const unsigned short* __restrict__ W1F,   // 512x256 fragment-major
    const unsigned short* __restrict__ W2F,   // 48x512 fragment-major
    __half* __restrict__ h2, __half* __restrict__ qb, int N) {
  __shared__ unsigned short sW1[16384];        // 32 KB: current ct chunk
  __shared__ unsigned short sHid[8][16][72];   // [wave][row][col] 18.4 KB
  __shared__ float sB1[512];
  __shared__ float sB2[64];

  int tid = threadIdx.x;
  int w = tid >> 6, lane = tid & 63;
  int q = lane >> 4, l15 = lane & 15;
  int row0 = blockIdx.x * 128 + w * 16;

  // issue ct=0 staging first: hides under the x-load phase
  {
    const unsigned short* gsrc = W1F + (w << 9) + lane * 8;
    unsigned short* ldst = &sW1[w << 9];
#pragma unroll
    for (int i = 0; i < 4; ++i)
      gl2lds16(gsrc + (i << 12), ldst + (i << 12));
  }
  sB1[tid] = b1[tid];
  if (tid < 48) sB2[tid] = b2[tid];

  // x ingest: 16 independent float4 loads issued before any conversion
  int grow = row0 + l15;
  bool rok = grow < N;
  const float* xr = x + (size_t)grow * D_IN;
  float4 xv[16];
#pragma unroll
  for (int jb = 0; jb < 8; ++jb) {
    xv[2 * jb]     = rok ? *(const float4*)(xr + jb * 32 + q * 8)
                         : make_float4(0.f, 0.f, 0.f, 0.f);
    xv[2 * jb + 1] = rok ? *(const float4*)(xr + jb * 32 + q * 8 + 4)
                         : make_float4(0.f, 0.f, 0.f, 0.f);
  }
  uint4 axu[8];
#pragma unroll
  for (int jb = 0; jb < 8; ++jb) {
    union { uint4 u; unsigned short s[8]; } uu;
    float4 v0 = xv[2 * jb], v1 = xv[2 * jb + 1];
    uu.s[0] = f2bf(v0.x); uu.s[1] = f2bf(v0.y); uu.s[2] = f2bf(v0.z); uu.s[3] = f2bf(v0.w);
    uu.s[4] = f2bf(v1.x); uu.s[5] = f2bf(v1.y); uu.s[6] = f2bf(v1.z); uu.s[7] = f2bf(v1.w);
    axu[jb] = uu.u;
  }

  f32x4 hacc[3];
#pragma unroll
  for (int t = 0; t < 3; ++t)
#pragma unroll
    for (int r = 0; r < 4; ++r) hacc[t][r] = 0.f;

  __syncthreads();   // ct=0 staged (vmcnt drained) + biases visible

  for (int ct = 0; ct < 8; ++ct) {
    int c0 = ct * 64;
    f32x4 acc[4];
#pragma unroll
    for (int t = 0; t < 4; ++t)
#pragma unroll
      for (int r = 0; r < 4; ++r) acc[t][r] = 0.f;

    const unsigned short* sb = &sW1[lane * 8];
#pragma unroll
    for (int kb = 0; kb < 8; ++kb) {
      bf16x8 a = __builtin_bit_cast(bf16x8, axu[kb]);
      bf16x8 bq0 = *(const bf16x8*)(sb + (kb << 9));
      bf16x8 bq1 = *(const bf16x8*)(sb + (kb << 9) + 4096);
      bf16x8 bq2 = *(const bf16x8*)(sb + (kb << 9) + 8192);
      bf16x8 bq3 = *(const bf16x8*)(sb + (kb << 9) + 12288);
      acc[0] = __builtin_amdgcn_mfma_f32_16x16x32_bf16(a, bq0, acc[0], 0, 0, 0);
      acc[1] = __builtin_amdgcn_mfma_f32_16x16x32_bf16(a, bq1, acc[1], 0, 0, 0);
      acc[2] = __builtin_amdgcn_mfma_f32_16x16x32_bf16(a, bq2, acc[2], 0, 0, 0);
      acc[3] = __builtin_amdgcn_mfma_f32_16x16x32_bf16(a, bq3, acc[3], 0, 0, 0);
    }
    // relu(acc + b1) -> wave-private sHid (C-layout: col=l15, row=q*4+rg)
#pragma unroll
    for (int tn = 0; tn < 4; ++tn) {
      int c = tn * 16 + l15;
      float bias = sB1[c0 + c];
#pragma unroll
      for (int rg = 0; rg < 4; ++rg) {
        float v = acc[tn][rg] + bias;
        v = v > 0.f ? v : 0.f;
        sHid[w][q * 4 + rg][c] = f2bf(v);
      }
    }
    // GEMM2 on this 64-col hid chunk (A from LDS, B direct from W2F)
#pragma unroll
    for (int kk = 0; kk < 2; ++kk) {
      bf16x8 a0 = *(const bf16x8*)&sHid[w][l15][kk * 32 + q * 8];
      const unsigned short* w2b = W2F + (((ct * 2 + kk) * 3) << 9) + lane * 8;
#pragma unroll
      for (int tn = 0; tn < 3; ++tn) {
        bf16x8 b = *(const bf16x8*)(w2b + (tn << 9));
        hacc[tn] = __builtin_amdgcn_mfma_f32_16x16x32_bf16(a0, b, hacc[tn], 0, 0, 0);
      }
    }
    // stage next ct chunk
    __syncthreads();   // all waves done reading sW1
    if (ct < 7) {
      const unsigned short* gsrc = W1F + ((size_t)(ct + 1) << 14) + (w << 9) + lane * 8;
      unsigned short* ldst = &sW1[w << 9];
#pragma unroll
      for (int i = 0; i < 4; ++i)
        gl2lds16(gsrc + (i << 12), ldst + (i << 12));
      __syncthreads();   // staged data visible
    }
  }
  // epilogue: h2 = f16(h), qb = f16(dinv*h); pad cols 48..63 zeroed in both
  float dv[4];
#pragma unroll
  for (int rg = 0; rg < 4; ++rg) {
    int gr = row0 + q * 4 + rg;
    dv[rg] = (gr < N) ? dinvp[gr] : 0.f;
  }
#pragma unroll
  for (int tn = 0; tn < 3; ++tn) {
    int c = tn * 16 + l15;
    float bias = sB2[c];
#pragma unroll
    for (int rg = 0; rg < 4; ++rg) {
      int gr = row0 + q * 4 + rg;
      if (gr < N) {
        float val = hacc[tn][rg] + bias;
        h2[(size_t)gr * HPAD + c] = __float2half(val);
        qb[(size_t)gr * HPAD + c] = __float2half(dv[rg] * val);
      }
    }
  }
#pragma unroll
  for (int rg = 0; rg < 4; ++rg) {
    int gr = row0 + q * 4 + rg;
    if (gr < N) {
      h2[(size_t)gr * HPAD + 48 + l15] = __float2half(0.f);
      qb[(size_t)gr * HPAD + 48 + l15] = __float2half(0.f);
    }
  }
}

// ---------------- APPNP propagation in q-space: 2 nodes/wave, unroll-4 ----------
// (R4 version, best measured.) cur holds q = dinv*out. Edges are 4-B src
// indices; self-loop is an ordinary slot; tails/dummies point at zeroed row N.
// out = 0.9*di*sum(q) + 0.1*h; nxt stores di*out, last stores out as f32.

__global__ __launch_bounds__(256) void prop_kernel(
    const __half* __restrict__ cur, const __half* __restrict__ h2,
    const float* __restrict__ dinv, const int* __restrict__ row_ptr,
    const int* __restrict__ edges, __half* __restrict__ nxt,
    float* __restrict__ outf, int N, int last) {
  int wid = (blockIdx.x * 256 + threadIdx.x) >> 6;
  int lane = threadIdx.x & 63;
  int half = lane >> 5;
  int slot = (lane >> 3) & 3;
  int s = lane & 7;
  int node = wid * 2 + half;
  bool nok = node < N;
  int p0 = 0, p1 = 0;
  if (nok) { int2 pp = *(const int2*)(row_ptr + node); p0 = pp.x; p1 = pp.y; }
  int d = p1 - p0;                          // padded degree (mult of 4, incl self)
  int dmax = max(d, __shfl_xor(d, 32));     // pair max (wave-uniform)
  int nb = dmax >> 2;

  float acc[8];
#pragma unroll
  for (int i = 0; i < 8; ++i) acc[i] = 0.f;

  int p = p0 + slot;
  int e0 = N, e1 = N, e2 = N, e3 = N;
  if (nb > 0) e0 = edges[p];
  if (nb > 1) e1 = edges[p + 4];
  if (nb > 2) e2 = edges[p + 8];
  if (nb > 3) e3 = edges[p + 12];
  int b = 0;
  for (; b + 4 <= nb; b += 4) {
    int n0 = N, n1 = N, n2 = N, n3 = N;
    if (b + 4 < nb) n0 = edges[p + 16];     // prefetch (uniform branches)
    if (b + 5 < nb) n1 = edges[p + 20];
    if (b + 6 < nb) n2 = edges[p + 24];
    if (b + 7 < nb) n3 = edges[p + 28];
    int i0 = (p      < p1) ? e0 : N;
    int i1 = (p + 4  < p1) ? e1 : N;
    int i2 = (p + 8  < p1) ? e2 : N;
    int i3 = (p + 12 < p1) ? e3 : N;
    union { float4 f; __half2 h[4]; } u0, u1, u2, u3;
    u0.f = *(const float4*)(cur + ((size_t)i0 << 6) + s * 8);
    u1.f = *(const float4*)(cur + ((size_t)i1 << 6) + s * 8);
    u2.f = *(const float4*)(cur + ((size_t)i2 << 6) + s * 8);
    u3.f = *(const float4*)(cur + ((size_t)i3 << 6) + s * 8);
#pragma unroll
    for (int i = 0; i < 4; ++i) {
      float2 f0 = __half22float2(u0.h[i]);
      float2 f1 = __half22float2(u1.h[i]);
      float2 f2 = __half22float2(u2.h[i]);
      float2 f3 = __half22float2(u3.h[i]);
      acc[2 * i]     += (f0.x + f1.x) + (f2.x + f3.x);
      acc[2 * i + 1] += (f0.y + f1.y) + (f2.y + f3.y);
    }
    e0 = n0; e1 = n1; e2 = n2; e3 = n3; p += 16;
  }
  // tail: up to 3 remaining 4-slot groups, records already in e0..e2
  if (b < nb) {
    int i0 = (p < p1) ? e0 : N;
    union { float4 f; __half2 h[4]; } u0;
    u0.f = *(const float4*)(cur + ((size_t)i0 << 6) + s * 8);
#pragma unroll
    for (int i = 0; i < 4; ++i) {
      float2 f0 = __half22float2(u0.h[i]);
      acc[2 * i]     += f0.x;
      acc[2 * i + 1] += f0.y;
    }
  }
  if (b + 1 < nb) {
    int i1 = (p + 4 < p1) ? e1 : N;
    union { float4 f; __half2 h[4]; } u1;
    u1.f = *(const float4*)(cur + ((size_t)i1 << 6) + s * 8);
#pragma unroll
    for (int i = 0; i < 4; ++i) {
      float2 f1 = __half22float2(u1.h[i]);
      acc[2 * i]     += f1.x;
      acc[2 * i + 1] += f1.y;
    }
  }
  if (b + 2 < nb) {
    int i2 = (p + 8 < p1) ? e2 : N;
    union { float4 f; __half2 h[4]; } u2;
    u2.f = *(const float4*)(cur + ((size_t)i2 << 6) + s * 8);
#pragma unroll
    for (int i = 0; i < 4; ++i) {
      float2 f2 = __half22float2(u2.h[i]);
      acc[2 * i]     += f2.x;
      acc[2 * i + 1] += f2.y;
    }
  }
  // fold the 4 slots (lane bits 3,4) via fixed-pattern swizzles
#pragma unroll
  for (int i = 0; i < 8; ++i) {
    acc[i] += __int_as_float(__builtin_amdgcn_ds_swizzle(__float_as_int(acc[i]), 0x201F)); // ^8
    acc[i] += __int_as_float(__builtin_amdgcn_ds_swizzle(__float_as_int(acc[i]), 0x401F)); // ^16
  }
  if ((lane & 24) != 0 || !nok) return;
  float di = dinv[node];
  size_t base = ((size_t)node << 6) + s * 8;
  union { float4 f; __half2 h[4]; } uh;
  uh.f = *(const float4*)(h2 + base);
  float outv[8];
#pragma unroll
  for (int i = 0; i < 4; ++i) {
    float2 hf = __half22float2(uh.h[i]);
    outv[2 * i]     = 0.9f * di * acc[2 * i]     + 0.1f * hf.x;
    outv[2 * i + 1] = 0.9f * di * acc[2 * i + 1] + 0.1f * hf.y;
  }
  if (last) {
    if (s < 6) {  // only the 48 real features
      float* op = outf + (size_t)node * D_OUT + s * 8;
      *(float4*)op       = make_float4(outv[0], outv[1], outv[2], outv[3]);
      *(float4*)(op + 4) = make_float4(outv[4], outv[5], outv[6], outv[7]);
    }
  } else {
    union { uint4 u4; __half2 h[4]; } o;
#pragma unroll
    for (int i = 0; i < 4; ++i)
      o.h[i] = __floats2half2_rn(di * outv[2 * i], di * outv[2 * i + 1]);
    *(uint4*)(nxt + base) = o.u4;
  }
}

// ---------------- launch ----------------

extern "C" void kernel_launch(void* const* d_in, const int* in_sizes, int n_in,
                              void* d_out, int out_size, void* d_ws, size_t ws_size,
                              hipStream_t stream) {
  (void)n_in; (void)out_size; (void)ws_size;
  const float* x  = (const float*)d_in[0];
  const int*   ei = (const int*)d_in[1];
  const float* W1 = (const float*)d_in[2];
  const float* b1 = (const float*)d_in[3];
  const float* W2 = (const float*)d_in[4];
  const float* b2 = (const float*)d_in[5];
  const int N = in_sizes[0] / D_IN;
  const int E = in_sizes[1] / 2;
  const int* e_src = ei;
  const int* e_dst = ei + E;

  char* ws = (char*)d_ws;
  size_t off = 0;
  auto take = [&](size_t bytes) -> char* {
    char* p = ws + off;
    off += (bytes + 511) & ~(size_t)511;
    return p;
  };
  int* cnt      = (int*)take((size_t)N * 4);
  float* dinv   = (float*)take((size_t)N * 4);
  int* row_ptr  = (int*)take((size_t)(N + 1) * 4);
  int* bsum     = (int*)take(1024);
  int* bofs     = (int*)take(1024);
  int* rank     = (int*)take((size_t)E * 4);
  int* edges    = (int*)take(((size_t)E + 4 * (size_t)N + 2048) * 4);  // padded CSR (4-B recs)
  unsigned short* W1F = (unsigned short*)take((size_t)D_IN * D_HID * 2);
  unsigned short* W2F = (unsigned short*)take((size_t)D_HID * D_OUT * 2);
  __half* h2    = (__half*)take((size_t)N * HPAD * 2);
  __half* bufA  = (__half*)take((size_t)(N + 1) * HPAD * 2);
  __half* bufB  = (__half*)d_out;   // 19.2 MB f32 out region holds (N+1)*128B f16 buf;
                                    // it10 reads bufA and writes f32 here -> no alias
  float* outp   = (float*)d_out;

  int nb256 = (N + 255) / 256;
  int eb256 = (E + 255) / 256;
  int NB    = (N + 1023) / 1024;   // 98 <= 128 ok

  // graph build (padded CSR, q-space: 4-B edge records, self-loop folded in)
  zero1_kernel<<<nb256, 256, 0, stream>>>(cnt, N);
  count_kernel<<<eb256, 256, 0, stream>>>(e_dst, cnt, rank, E);
  dinv_kernel<<<nb256, 256, 0, stream>>>(cnt, dinv, N);
  scan1_kernel<<<NB, 256, 0, stream>>>(cnt, row_ptr, bsum, N);
  scan2_kernel<<<1, 128, 0, stream>>>(bsum, bofs, row_ptr, NB, N);
  scan3_kernel<<<NB, 256, 0, stream>>>(row_ptr, bofs, N);
  fill_kernel<<<eb256, 256, 0, stream>>>(e_src, e_dst, row_ptr, rank, edges, E);
  pad_kernel<<<nb256, 256, 0, stream>>>(cnt, row_ptr, edges, N);
  zrow_kernel<<<1, 64, 0, stream>>>(bufA, bufB, N);

  // weight permute + encoder (emits h2 and q0 into bufB)
  convert_w1<<<(D_IN * D_HID + 255) / 256, 256, 0, stream>>>(W1, W1F);
  convert_w2<<<(D_HID * D_OUT + 255) / 256, 256, 0, stream>>>(W2, W2F);
  encoder_kernel<<<(N + 127) / 128, 512, 0, stream>>>(x, b1, b2, dinv, W1F, W2F,
                                                      h2, bufB, N);

  // APPNP: 10 iters in q-space; q0(bufB) -> A -> B -> ... ; last writes f32 d_out
  int waves = (N + 1) / 2;
  int pblocks = (waves + 3) / 4;
  const __half* src = bufB;
  __half* dst = bufA;
  for (int it = 1; it <= K_STEPS; ++it) {
    int last = (it == K_STEPS);
    prop_kernel<<<pblocks, 256, 0, stream>>>(src, h2, dinv, row_ptr, edges,
                                             dst, outp, N, last);
    src = dst;
    dst = (dst == bufA) ? bufB : bufA;
  }
}